// Round 3
// baseline (872.499 us; speedup 1.0000x reference)
//
#include <hip/hip_runtime.h>
#include <math.h>

constexpr int kE = 32;    // experts
constexpr int kH = 2048;  // hidden
constexpr int kI = 768;   // expert intermediate dim
constexpr int kT = 2048;  // tokens
constexpr int kK = 4;     // top-k

typedef _Float16 half8  __attribute__((ext_vector_type(8)));
typedef _Float16 half4v __attribute__((ext_vector_type(4)));
typedef float    float4v __attribute__((ext_vector_type(4)));

// Workspace layout (bytes):
//   [0,256)        expert_offsets int[kE+1]
//   [256,..)       token_ids int[8192]
//   [33024,..)     token_w  float[8192]
//   [65792,..)     inv      int[8192]         (slot id per (t,k), -1 if dup)
//   [98560,..)     gated    _Float16[8192][768]   (~12.6 MB)
//   [12681472,..)  eo       float[8192][2048]     (~67 MB, weighted expert out)
//   [79790336,..)  hs16     _Float16[2048][2048]  (~8.4 MB)
constexpr size_t kOffsOff  = 0;
constexpr size_t kTokOff   = 256;
constexpr size_t kTwOff    = 33024;
constexpr size_t kInvOff   = 65792;
constexpr size_t kGatedOff = 98560;
constexpr size_t kEoOff    = 12681472;
constexpr size_t kHs16Off  = 79790336;

// ---------------------------------------------------------------------------
// Routing. numpy scatter semantics: last duplicate wins, expert contributes
// once. R3: also emits inverse map inv[t*4+k] = slot (or -1 for shadowed
// duplicates) so the combine kernel can gather without atomics.
// ---------------------------------------------------------------------------
__global__ __launch_bounds__(256) void route_kernel(
    const int* __restrict__ ridx, const float* __restrict__ rw,
    int* __restrict__ offs, int* __restrict__ tok, float* __restrict__ tw,
    int* __restrict__ inv) {
  __shared__ int s_cnt[kE];
  __shared__ int s_off[kE + 1];
  __shared__ int s_cur[kE];
  const int tid = threadIdx.x;
  if (tid < kE) { s_cnt[tid] = 0; s_cur[tid] = 0; }
  __syncthreads();
  for (int i = tid; i < kT * kK; i += 256) {
    const int t = i >> 2, k = i & 3;
    const int e = ridx[i];
    bool last = true;
    for (int k2 = k + 1; k2 < kK; ++k2)
      if (ridx[t * kK + k2] == e) last = false;
    if (last) atomicAdd(&s_cnt[e], 1);
  }
  __syncthreads();
  if (tid == 0) {
    int acc = 0;
    for (int e = 0; e < kE; ++e) { s_off[e] = acc; acc += s_cnt[e]; }
    s_off[kE] = acc;
  }
  __syncthreads();
  if (tid <= kE) offs[tid] = s_off[tid];
  for (int i = tid; i < kT * kK; i += 256) {
    const int t = i >> 2, k = i & 3;
    const int e = ridx[i];
    bool last = true;
    for (int k2 = k + 1; k2 < kK; ++k2)
      if (ridx[t * kK + k2] == e) last = false;
    int g = -1;
    if (last) {
      const int p = atomicAdd(&s_cur[e], 1);
      g = s_off[e] + p;
      tok[g] = t;
      tw[g] = rw[i];
    }
    inv[i] = g;
  }
}

// ---------------------------------------------------------------------------
// hs fp32 -> fp16 pre-pass. Removes per-use cvt and halves the x12 re-read
// traffic of the activation operand in gateup.
// ---------------------------------------------------------------------------
__global__ __launch_bounds__(256) void hs16_kernel(
    const float* __restrict__ hs, _Float16* __restrict__ hs16) {
  const size_t i = ((size_t)blockIdx.x * 256 + threadIdx.x) * 8;
  const float4v v0 = *(const float4v*)(hs + i);
  const float4v v1 = *(const float4v*)(hs + i + 4);
  half8 h;
  h[0] = (_Float16)v0[0]; h[1] = (_Float16)v0[1];
  h[2] = (_Float16)v0[2]; h[3] = (_Float16)v0[3];
  h[4] = (_Float16)v1[0]; h[5] = (_Float16)v1[1];
  h[6] = (_Float16)v1[2]; h[7] = (_Float16)v1[3];
  *(half8*)(hs16 + i) = h;
}

// ---------------------------------------------------------------------------
// Gate-up MFMA kernel. R3: token tile 64 (was 128) -> 1536 active blocks =
// 6/CU for latency hiding; acc halves to 8 float4v/wave. A operand from fp16
// hs16 (single half8 load/thread/phase). Dense e-major block decode keeps all
// slices of an expert on one XCD ((x+512y)%8 == e%8) for L2 reuse.
// ---------------------------------------------------------------------------
__global__ __launch_bounds__(256) void gateup_kernel(
    const _Float16* __restrict__ hs16, const float* __restrict__ gup,
    const int* __restrict__ offs, const int* __restrict__ tok,
    _Float16* __restrict__ gated) {
  const int e  = blockIdx.x & 31;   // dense active IDs: e fast, tt slow
  const int tt = blockIdx.x >> 5;   // 0..31
  const int base = offs[e];
  const int Ne = offs[e + 1] - base;
  if (tt * 64 >= Ne) return;
  const int i0 = blockIdx.y * 64;
  const int total = offs[kE];

  __shared__ _Float16 Asb[64 * 40];   // [row][k] k-contiguous, stride 40
  __shared__ _Float16 Bsb[128 * 40];  // [n][k]; n<64 gate, n>=64 up

  const int tid = threadIdx.x;
  // A staging: thread owns row ar, k-chunk ak8..ak8+7 (one half8)
  const int ar  = tid >> 2;         // 0..63
  const int ak8 = (tid & 3) * 8;    // 0,8,16,24
  int slot = base + tt * 64 + ar;
  slot = slot < total ? slot : total - 1;
  const size_t arow = (size_t)tok[slot] * kH;
  // B staging: thread owns col n=bn, k-chunks bk+16p (p<2), 4 k each
  const int bn = tid & 63;
  const int bk = (tid >> 6) * 4;
  const float* gupe = gup + (size_t)e * kH * (2 * kI);

  const int lane = tid & 63, wave = tid >> 6;
  const int m16 = lane & 15, quad = lane >> 4;
  const int wm = wave >> 1, wn = wave & 1;

  float4v accg[2][2], accu[2][2];
#pragma unroll
  for (int mt = 0; mt < 2; ++mt)
#pragma unroll
    for (int nt = 0; nt < 2; ++nt) {
      accg[mt][nt] = (float4v){0.f, 0.f, 0.f, 0.f};
      accu[mt][nt] = (float4v){0.f, 0.f, 0.f, 0.f};
    }

  // ---- double-buffered register staging ----
  half8 avA, avB;
  float bgA[2][4], buA[2][4], bgB[2][4], buB[2][4];

  auto gload = [&](int kk, half8& av, float (&bg)[2][4], float (&bu)[2][4]) {
    av = *(const half8*)(hs16 + arow + kk + ak8);
#pragma unroll
    for (int p = 0; p < 2; ++p) {
      const int k0 = bk + 16 * p;
      const float* bp = gupe + (size_t)(kk + k0) * (2 * kI) + i0 + bn;
#pragma unroll
      for (int j = 0; j < 4; ++j) {
        bg[p][j] = bp[(size_t)j * (2 * kI)];
        bu[p][j] = bp[(size_t)j * (2 * kI) + kI];
      }
    }
  };

  auto lstore = [&](const half8& av, const float (&bg)[2][4],
                    const float (&bu)[2][4]) {
    *(half8*)&Asb[ar * 40 + ak8] = av;
#pragma unroll
    for (int p = 0; p < 2; ++p) {
      const int k0 = bk + 16 * p;
      *(half4v*)&Bsb[bn * 40 + k0] =
          (half4v){(_Float16)bg[p][0], (_Float16)bg[p][1],
                   (_Float16)bg[p][2], (_Float16)bg[p][3]};
      *(half4v*)&Bsb[(bn + 64) * 40 + k0] =
          (half4v){(_Float16)bu[p][0], (_Float16)bu[p][1],
                   (_Float16)bu[p][2], (_Float16)bu[p][3]};
    }
  };

  auto compute = [&]() {
    half8 af[2];
#pragma unroll
    for (int mt = 0; mt < 2; ++mt)
      af[mt] = *(const half8*)&Asb[(wm * 32 + mt * 16 + m16) * 40 + quad * 8];
    half8 bfg[2], bfu[2];
#pragma unroll
    for (int nt = 0; nt < 2; ++nt) {
      bfg[nt] = *(const half8*)&Bsb[(wn * 32 + nt * 16 + m16) * 40 + quad * 8];
      bfu[nt] =
          *(const half8*)&Bsb[(64 + wn * 32 + nt * 16 + m16) * 40 + quad * 8];
    }
#pragma unroll
    for (int mt = 0; mt < 2; ++mt)
#pragma unroll
      for (int nt = 0; nt < 2; ++nt) {
        accg[mt][nt] = __builtin_amdgcn_mfma_f32_16x16x32_f16(
            af[mt], bfg[nt], accg[mt][nt], 0, 0, 0);
        accu[mt][nt] = __builtin_amdgcn_mfma_f32_16x16x32_f16(
            af[mt], bfu[nt], accu[mt][nt], 0, 0, 0);
      }
  };

  gload(0, avA, bgA, buA);
  for (int kk = 0; kk < kH; kk += 64) {
    __syncthreads();               // prev frag reads done; LDS reusable
    lstore(avA, bgA, buA);
    gload(kk + 32, avB, bgB, buB); // in flight across compute phase
    __syncthreads();
    compute();
    __syncthreads();
    lstore(avB, bgB, buB);
    if (kk + 64 < kH) gload(kk + 64, avA, bgA, buA);
    __syncthreads();
    compute();
  }

  // epilogue: SwiGLU, store fp16 gated. D layout: row=quad*4+r, col=m16.
#pragma unroll
  for (int mt = 0; mt < 2; ++mt)
#pragma unroll
    for (int r = 0; r < 4; ++r) {
      const int rr = tt * 64 + wm * 32 + mt * 16 + quad * 4 + r;
      if (rr < Ne) {
        _Float16* gp = gated + (size_t)(base + rr) * kI + i0 + wn * 32 + m16;
#pragma unroll
        for (int nt = 0; nt < 2; ++nt) {
          const float g = accg[mt][nt][r];
          const float u = accu[mt][nt][r];
          gp[nt * 16] = (_Float16)(u * g / (1.f + expf(-g)));
        }
      }
    }
}

// ---------------------------------------------------------------------------
// Down-proj MFMA kernel. R3: token tile 64 -> 2048 active blocks = 8/CU.
// Epilogue: plain weighted fp32 stores into eo[slot][H] (atomics removed).
// ---------------------------------------------------------------------------
__global__ __launch_bounds__(256) void down_kernel(
    const _Float16* __restrict__ gated, const float* __restrict__ dn,
    const int* __restrict__ offs, const int* __restrict__ tok,
    const float* __restrict__ tw, float* __restrict__ eo) {
  const int e  = blockIdx.x & 31;   // dense active IDs
  const int tt = blockIdx.x >> 5;   // 0..31
  const int base = offs[e];
  const int Ne = offs[e + 1] - base;
  if (tt * 64 >= Ne) return;
  const int h0 = blockIdx.y * 128;
  const int total = offs[kE];

  __shared__ _Float16 Asb[64 * 40];
  __shared__ _Float16 Bsb[128 * 40];

  const int tid = threadIdx.x;
  // A staging: thread owns row ar, k-chunk ak8..ak8+7 (one half8)
  const int ar  = tid >> 2;         // 0..63
  const int ak8 = (tid & 3) * 8;
  int slotc = base + tt * 64 + ar;
  slotc = slotc < total ? slotc : total - 1;
  const size_t arow = (size_t)slotc * kI;
  // B staging: col n = tid&127; k-chunks bk+8g (g<4), 4 k each
  const int bn = tid & 127;
  const int bk = (tid >> 7) * 4;    // 0 or 4
  const float* dne = dn + (size_t)e * kI * kH;

  const int lane = tid & 63, wave = tid >> 6;
  const int m16 = lane & 15, quad = lane >> 4;
  const int wm = wave >> 1, wn = wave & 1;

  float4v acc[2][4];
#pragma unroll
  for (int mt = 0; mt < 2; ++mt)
#pragma unroll
    for (int nt = 0; nt < 4; ++nt) acc[mt][nt] = (float4v){0.f, 0.f, 0.f, 0.f};

  // ---- double-buffered register staging ----
  half8 a8A, a8B;
  float bwA[4][4], bwB[4][4];

  auto gload = [&](int kk, half8& a8, float (&bw)[4][4]) {
    a8 = *(const half8*)(gated + arow + kk + ak8);
#pragma unroll
    for (int g = 0; g < 4; ++g) {
      const int k0 = bk + 8 * g;
#pragma unroll
      for (int j = 0; j < 4; ++j)
        bw[g][j] = dne[(size_t)(kk + k0 + j) * kH + h0 + bn];
    }
  };

  auto lstore = [&](const half8& a8, const float (&bw)[4][4]) {
    *(half8*)&Asb[ar * 40 + ak8] = a8;
#pragma unroll
    for (int g = 0; g < 4; ++g) {
      const int k0 = bk + 8 * g;
      *(half4v*)&Bsb[bn * 40 + k0] =
          (half4v){(_Float16)bw[g][0], (_Float16)bw[g][1],
                   (_Float16)bw[g][2], (_Float16)bw[g][3]};
    }
  };

  auto compute = [&]() {
    half8 af[2], bf[4];
#pragma unroll
    for (int mt = 0; mt < 2; ++mt)
      af[mt] = *(const half8*)&Asb[(wm * 32 + mt * 16 + m16) * 40 + quad * 8];
#pragma unroll
    for (int nt = 0; nt < 4; ++nt)
      bf[nt] = *(const half8*)&Bsb[(wn * 64 + nt * 16 + m16) * 40 + quad * 8];
#pragma unroll
    for (int mt = 0; mt < 2; ++mt)
#pragma unroll
      for (int nt = 0; nt < 4; ++nt)
        acc[mt][nt] = __builtin_amdgcn_mfma_f32_16x16x32_f16(
            af[mt], bf[nt], acc[mt][nt], 0, 0, 0);
  };

  gload(0, a8A, bwA);
  for (int kk = 0; kk < kI; kk += 64) {
    __syncthreads();
    lstore(a8A, bwA);
    gload(kk + 32, a8B, bwB);
    __syncthreads();
    compute();
    __syncthreads();
    lstore(a8B, bwB);
    if (kk + 64 < kI) gload(kk + 64, a8A, bwA);
    __syncthreads();
    compute();
  }

  // epilogue: weighted plain stores into eo[slot][H]
#pragma unroll
  for (int mt = 0; mt < 2; ++mt)
#pragma unroll
    for (int r = 0; r < 4; ++r) {
      const int rr = tt * 64 + wm * 32 + mt * 16 + quad * 4 + r;
      if (rr < Ne) {
        const int s = base + rr;
        const float w = tw[s];
        float* op = eo + (size_t)s * kH + h0 + wn * 64 + m16;
#pragma unroll
        for (int nt = 0; nt < 4; ++nt)
          op[nt * 16] = acc[mt][nt][r] * w;
      }
    }
}

// ---------------------------------------------------------------------------
// Combine: out[t][:] = sum over this token's valid slots of eo[slot][:].
// Fully coalesced streaming; replaces 64M atomics + output memset.
// ---------------------------------------------------------------------------
__global__ __launch_bounds__(256) void combine_kernel(
    const float* __restrict__ eo, const int* __restrict__ inv,
    float* __restrict__ out) {
  const int t = blockIdx.x;
  const int iv0 = inv[t * 4 + 0], iv1 = inv[t * 4 + 1];
  const int iv2 = inv[t * 4 + 2], iv3 = inv[t * 4 + 3];
  const int tid = threadIdx.x;
  for (int h = tid * 4; h < kH; h += 1024) {
    float4v a = (float4v){0.f, 0.f, 0.f, 0.f};
    if (iv0 >= 0) a += *(const float4v*)(eo + (size_t)iv0 * kH + h);
    if (iv1 >= 0) a += *(const float4v*)(eo + (size_t)iv1 * kH + h);
    if (iv2 >= 0) a += *(const float4v*)(eo + (size_t)iv2 * kH + h);
    if (iv3 >= 0) a += *(const float4v*)(eo + (size_t)iv3 * kH + h);
    *(float4v*)(out + (size_t)t * kH + h) = a;
  }
}

extern "C" void kernel_launch(void* const* d_in, const int* in_sizes, int n_in,
                              void* d_out, int out_size, void* d_ws, size_t ws_size,
                              hipStream_t stream) {
  const float* hs   = (const float*)d_in[0];
  const float* rw   = (const float*)d_in[1];
  const int*   ridx = (const int*)d_in[2];
  const float* gup  = (const float*)d_in[4];
  const float* dn   = (const float*)d_in[5];
  float* out = (float*)d_out;

  char* ws = (char*)d_ws;
  int*      offs  = (int*)(ws + kOffsOff);
  int*      tok   = (int*)(ws + kTokOff);
  float*    tw    = (float*)(ws + kTwOff);
  int*      inv   = (int*)(ws + kInvOff);
  _Float16* gated = (_Float16*)(ws + kGatedOff);
  float*    eo    = (float*)(ws + kEoOff);
  _Float16* hs16  = (_Float16*)(ws + kHs16Off);

  route_kernel<<<1, 256, 0, stream>>>(ridx, rw, offs, tok, tw, inv);
  hs16_kernel<<<(kT * kH) / (256 * 8), 256, 0, stream>>>(hs, hs16);
  gateup_kernel<<<dim3(32 * 32, kI / 64), 256, 0, stream>>>(hs16, gup, offs, tok, gated);
  down_kernel<<<dim3(32 * 32, kH / 128), 256, 0, stream>>>(gated, dn, offs, tok, tw, eo);
  combine_kernel<<<kT, 256, 0, stream>>>(eo, inv, out);
}